// Round 13
// baseline (14.245 us; speedup 1.0000x reference)
//
#include <hip/hip_runtime.h>

// B-spline activation (KAN-style), fp32.
// x: (8192, 1024) f32, coeff: (1024, 10) f32, out: (8192, 1024) f32.
// Structure: per-(feature,interval) power-basis float4 in LDS; tap = ONE
// ds_read_b128 (j-independent banks); 3 Horner FMAs; NT out stores; coeff
// loads issued before x loads (in-order vmcnt queue, r6/r12 lesson).
// Round-13 lever: PROWS=64 -> 13KB LDS -> GRID=2048 one-generation with
// 8 blocks/CU x 4 waves = 32 waves/CU (2x in-flight memory vs r10's 16),
// at constant 256-thread block shape (r11's 512-thread test was confounded
// by barrier width + idle staging waves).

typedef float f32x4 __attribute__((ext_vector_type(4)));

constexpr int NB = 10;           // N_BASES
constexpr int THREADS = 256;
constexpr int GRID = 2048;
constexpr int ITERS = 4;
constexpr int PROWS = 64;        // features per panel (16 panels)
constexpr int NJ = 13;           // intervals

__global__ __launch_bounds__(THREADS) void bspline_act_kernel(
    const float* __restrict__ x,
    const float* __restrict__ coeff,
    float* __restrict__ out)
{
    // lds4[j*PROWS + s]; slot s holds logical row r(s) = ((s&15)<<2)|(s>>4),
    // so the reader of feature-group fg, element e hits slot e*16+fg
    // (consecutive 16B chunks; plane stride 1024B -> banks j-independent;
    // the 4 wr-quarters of a wave broadcast).
    __shared__ float4 lds4[NJ * PROWS];          // 13 KB; x8 blocks = 104 KB/CU
    const int t = threadIdx.x;
    const int b = blockIdx.x;
    const int panel = b & 15;                    // 64-feature panel
    const int rg = b >> 4;                       // 0..127
    const int fg = t & 15;                       // feature group (4 features)
    const int wr = t >> 4;                       // 0..15: batch row in stripe

    const bool stager = (t < PROWS);             // threads 0..63 stage
    // Phase 1: coeff loads first (oldest in the in-order vmcnt queue).
    float2 c0, c1, c2, c3, c4;
    if (stager) {
        const float* src = coeff + (panel * PROWS + t) * NB;
        const float2* s2 = reinterpret_cast<const float2*>(src);
        c0 = s2[0]; c1 = s2[1]; c2 = s2[2]; c3 = s2[3]; c4 = s2[4];
    }

    // Phase 2: issue all 4 x loads (all threads) — in flight under the build.
    float4 xv[ITERS];
    int E4[ITERS];
    #pragma unroll
    for (int k = 0; k < ITERS; ++k) {
        const int row = (rg + k * 128) * 16 + wr;        // batch row
        E4[k] = row * 256 + panel * 16 + fg;             // float4 index
        xv[k] = reinterpret_cast<const float4*>(x)[E4[k]];
    }

    // Phase 3: build 13 interval-polynomials (waits only on coeff loads).
    if (stager) {
        float w[16];
        w[0] = w[1] = w[2] = 0.0f;
        w[13] = w[14] = w[15] = 0.0f;
        w[3] = c0.x;  w[4] = c0.y;  w[5] = c1.x;  w[6] = c1.y;
        w[7] = c2.x;  w[8] = c2.y;  w[9] = c3.x;  w[10] = c3.y;
        w[11] = c4.x; w[12] = c4.y;
        const int slot = ((t & 3) << 4) | (t >> 2);      // inverse row swizzle
        #pragma unroll
        for (int j = 0; j < NJ; ++j) {
            const float d0 = w[j], d1 = w[j + 1], d2 = w[j + 2], d3 = w[j + 3];
            float4 a;
            a.x = fmaf(4.0f, d1, d0 + d2) * (1.0f / 6.0f);      // a0
            a.y = (d2 - d0) * 0.5f;                             // a1
            a.z = (d0 + d2) * 0.5f - d1;                        // a2
            a.w = (d3 - d0) * (1.0f / 6.0f) + (d1 - d2) * 0.5f; // a3
            lds4[j * PROWS + slot] = a;   // bijective slots: conflict-free
        }
    }
    __syncthreads();

    const float4* lbase = lds4 + fg;    // + e*16 + j*PROWS

    #pragma unroll
    for (int k = 0; k < ITERS; ++k) {
        const float xs[4] = {xv[k].x, xv[k].y, xv[k].z, xv[k].w};
        float res[4];
        #pragma unroll
        for (int e = 0; e < 4; ++e) {
            const float xc = fminf(fmaxf(xs[e], -1.0f), 1.0f);
            const float u = fmaf(xc, 6.5f, 6.5f);        // knot units [0,13]
            const float jf = fminf(truncf(u), 12.0f);
            const float tt = u - jf;                     // [0,1]
            const int j = (int)jf;

            const float4 a = lbase[e * 16 + j * PROWS];  // 1x ds_read_b128
            float r = fmaf(a.w, tt, a.z);
            r = fmaf(r, tt, a.y);
            r = fmaf(r, tt, a.x);
            // x==+1 (j=12, tt=1) / x==-1 (j=0, tt=0): zero pads give ~0
            // (<= ~1e-7), matching the reference's empty-indicator edges.
            res[e] = r;
        }
        const f32x4 ov = {res[0], res[1], res[2], res[3]};
        // NT: out is write-once, never read -> don't allocate in L2/L3.
        __builtin_nontemporal_store(ov, reinterpret_cast<f32x4*>(out) + E4[k]);
    }
}

extern "C" void kernel_launch(void* const* d_in, const int* in_sizes, int n_in,
                              void* d_out, int out_size, void* d_ws, size_t ws_size,
                              hipStream_t stream) {
    const float* x = (const float*)d_in[0];
    const float* coeff = (const float*)d_in[1];
    float* out = (float*)d_out;
    hipLaunchKernelGGL(bspline_act_kernel, dim3(GRID), dim3(THREADS), 0, stream,
                       x, coeff, out);
}

// Round 14
// 13.861 us; speedup vs baseline: 1.0277x; 1.0277x over previous
//
#include <hip/hip_runtime.h>

// B-spline activation (KAN-style), fp32 — FINAL (best config, r10: 13.70us).
// x: (8192, 1024) f32, coeff: (1024, 10) f32, out: (8192, 1024) f32.
//
// Structure: per-(feature, interval) power-basis float4 in LDS;
//   P_j(tt) = a0 + a1 tt + a2 tt^2 + a3 tt^3 (cardinal cubic B-spline,
//   uniform knots, pads = 0 reproduce the reference's empty-indicator edges).
// Tap fetch = ONE ds_read_b128, bank pattern j-INDEPENDENT (plane stride
// 2048B; lanes read consecutive 16B chunks; wr-halves broadcast).
// Inner math = 3 Horner FMAs. NT out stores (out never read -> no L2/L3
// allocation; r9: 15.9->14.4us). One block generation: GRID=1024 = 4
// blocks/CU all resident, staging paid once (r10: ->13.7us).
//
// Probed and rejected: 32 waves/CU via 512-thr blocks (r11: 14.2) and via
// 8x 13KB blocks (r13: 14.2); prologue load reorder (r12: neutral);
// scalar-tap layouts (r3/r4); block turnover (r5/r9). 16 waves/CU with
// this structure is the measured optimum; mixed R+W stream saturated.

typedef float f32x4 __attribute__((ext_vector_type(4)));

constexpr int NB = 10;           // N_BASES
constexpr int THREADS = 256;
constexpr int GRID = 1024;
constexpr int ITERS = 8;
constexpr int PROWS = 128;       // features per panel (8 panels)
constexpr int NJ = 13;           // intervals

__global__ __launch_bounds__(THREADS) void bspline_act_kernel(
    const float* __restrict__ x,
    const float* __restrict__ coeff,
    float* __restrict__ out)
{
    // lds4[j * PROWS + s]; slot s holds logical row r(s) = ((s&31)<<2)|(s>>5),
    // so the reader of feature-group fg, element e hits slot e*32+fg.
    __shared__ float4 lds4[NJ * PROWS];          // 26 KB -> 6 blocks/CU capacity
    const int t = threadIdx.x;
    const int b = blockIdx.x;
    const int panel = b & 7;                     // 128-feature panel
    const int rg = b >> 3;                       // 0..127
    const int fg = t & 31;                       // feature group (4 features)
    const int wr = t >> 5;                       // 0..7: batch row within stripe

    // Staging: threads 0..127 each build one row's 13 interval-polynomials.
    if (t < PROWS) {
        const int r = ((t & 31) << 2) | (t >> 5);        // r2(r) == t
        const float* src = coeff + (panel * PROWS + r) * NB;
        float w[16];
        w[0] = w[1] = w[2] = 0.0f;
        w[13] = w[14] = w[15] = 0.0f;
        #pragma unroll
        for (int c = 0; c < 5; ++c) {
            const float2 p = reinterpret_cast<const float2*>(src)[c];
            w[3 + 2 * c] = p.x;
            w[4 + 2 * c] = p.y;
        }
        #pragma unroll
        for (int j = 0; j < NJ; ++j) {
            const float d0 = w[j], d1 = w[j + 1], d2 = w[j + 2], d3 = w[j + 3];
            float4 a;
            a.x = fmaf(4.0f, d1, d0 + d2) * (1.0f / 6.0f);      // a0
            a.y = (d2 - d0) * 0.5f;                             // a1
            a.z = (d0 + d2) * 0.5f - d1;                        // a2
            a.w = (d3 - d0) * (1.0f / 6.0f) + (d1 - d2) * 0.5f; // a3
            lds4[j * PROWS + t] = a;   // consecutive slots per lane: conflict-free
        }
    }
    __syncthreads();

    // Hoist all x loads: 8 independent float4 loads in flight.
    float4 xv[ITERS];
    int E4[ITERS];
    #pragma unroll
    for (int k = 0; k < ITERS; ++k) {
        const int row = (rg + k * 128) * 8 + wr;         // batch row
        E4[k] = row * 256 + panel * 32 + fg;             // float4 index
        xv[k] = reinterpret_cast<const float4*>(x)[E4[k]];
    }

    const float4* lbase = lds4 + fg;    // + e*32 + j*PROWS

    #pragma unroll
    for (int k = 0; k < ITERS; ++k) {
        const float xs[4] = {xv[k].x, xv[k].y, xv[k].z, xv[k].w};
        float res[4];
        #pragma unroll
        for (int e = 0; e < 4; ++e) {
            const float xc = fminf(fmaxf(xs[e], -1.0f), 1.0f);
            const float u = fmaf(xc, 6.5f, 6.5f);        // knot units [0,13]
            const float jf = fminf(truncf(u), 12.0f);
            const float tt = u - jf;                     // [0,1]
            const int j = (int)jf;

            const float4 a = lbase[e * 32 + j * PROWS];  // 1x ds_read_b128
            float r = fmaf(a.w, tt, a.z);
            r = fmaf(r, tt, a.y);
            r = fmaf(r, tt, a.x);
            // x==+1 (j=12, tt=1) / x==-1 (j=0, tt=0): zero pads give ~0
            // (<= ~1e-7), matching the reference's empty-indicator edges.
            res[e] = r;
        }
        const f32x4 ov = {res[0], res[1], res[2], res[3]};
        // NT: out is write-once, never read -> don't allocate in L2/L3.
        __builtin_nontemporal_store(ov, reinterpret_cast<f32x4*>(out) + E4[k]);
    }
}

extern "C" void kernel_launch(void* const* d_in, const int* in_sizes, int n_in,
                              void* d_out, int out_size, void* d_ws, size_t ws_size,
                              hipStream_t stream) {
    const float* x = (const float*)d_in[0];
    const float* coeff = (const float*)d_in[1];
    float* out = (float*)d_out;
    hipLaunchKernelGGL(bspline_act_kernel, dim3(GRID), dim3(THREADS), 0, stream,
                       x, coeff, out);
}

// Round 15
// 13.415 us; speedup vs baseline: 1.0619x; 1.0333x over previous
//
#include <hip/hip_runtime.h>

// B-spline activation (KAN-style), fp32.
// x: (8192, 1024) f32, coeff: (1024, 10) f32, out: (8192, 1024) f32.
// Structure = r10/r14 best (13.7us): per-(feature,interval) power-basis
// float4 in LDS; tap = ONE ds_read_b128 (j-independent banks); 3 Horner
// FMAs; NT out stores; GRID=1024 (one resident generation, 4 blocks/CU,
// 16 waves/CU — measured optimum vs 8/32 waves).
// Round-15 lever: phase-split main loop. vmcnt counts STORES as well as
// loads; the r10 loop interleaved NT-store k with wait-for-load k+1, putting
// store RETIREMENT on the iteration dependency chain. Here: compute all 8
// results into registers first (waits only on loads), then issue all 8 NT
// stores with no dependent waits after them. +32 VGPR, occupancy unaffected.

typedef float f32x4 __attribute__((ext_vector_type(4)));

constexpr int NB = 10;           // N_BASES
constexpr int THREADS = 256;
constexpr int GRID = 1024;
constexpr int ITERS = 8;
constexpr int PROWS = 128;       // features per panel (8 panels)
constexpr int NJ = 13;           // intervals

__global__ __launch_bounds__(THREADS) void bspline_act_kernel(
    const float* __restrict__ x,
    const float* __restrict__ coeff,
    float* __restrict__ out)
{
    // lds4[j * PROWS + s]; slot s holds logical row r(s) = ((s&31)<<2)|(s>>5),
    // so the reader of feature-group fg, element e hits slot e*32+fg.
    __shared__ float4 lds4[NJ * PROWS];          // 26 KB
    const int t = threadIdx.x;
    const int b = blockIdx.x;
    const int panel = b & 7;                     // 128-feature panel
    const int rg = b >> 3;                       // 0..127
    const int fg = t & 31;                       // feature group (4 features)
    const int wr = t >> 5;                       // 0..7: batch row within stripe

    // Staging: threads 0..127 each build one row's 13 interval-polynomials.
    if (t < PROWS) {
        const int r = ((t & 31) << 2) | (t >> 5);        // r2(r) == t
        const float* src = coeff + (panel * PROWS + r) * NB;
        float w[16];
        w[0] = w[1] = w[2] = 0.0f;
        w[13] = w[14] = w[15] = 0.0f;
        #pragma unroll
        for (int c = 0; c < 5; ++c) {
            const float2 p = reinterpret_cast<const float2*>(src)[c];
            w[3 + 2 * c] = p.x;
            w[4 + 2 * c] = p.y;
        }
        #pragma unroll
        for (int j = 0; j < NJ; ++j) {
            const float d0 = w[j], d1 = w[j + 1], d2 = w[j + 2], d3 = w[j + 3];
            float4 a;
            a.x = fmaf(4.0f, d1, d0 + d2) * (1.0f / 6.0f);      // a0
            a.y = (d2 - d0) * 0.5f;                             // a1
            a.z = (d0 + d2) * 0.5f - d1;                        // a2
            a.w = (d3 - d0) * (1.0f / 6.0f) + (d1 - d2) * 0.5f; // a3
            lds4[j * PROWS + t] = a;   // consecutive slots per lane: conflict-free
        }
    }
    __syncthreads();

    // Phase A: hoist all 8 x loads.
    float4 xv[ITERS];
    int E4[ITERS];
    #pragma unroll
    for (int k = 0; k < ITERS; ++k) {
        const int row = (rg + k * 128) * 8 + wr;         // batch row
        E4[k] = row * 256 + panel * 32 + fg;             // float4 index
        xv[k] = reinterpret_cast<const float4*>(x)[E4[k]];
    }

    const float4* lbase = lds4 + fg;    // + e*32 + j*PROWS

    // Phase B: compute ALL results into registers (vmcnt waits = loads only).
    f32x4 ov[ITERS];
    #pragma unroll
    for (int k = 0; k < ITERS; ++k) {
        const float xs[4] = {xv[k].x, xv[k].y, xv[k].z, xv[k].w};
        float res[4];
        #pragma unroll
        for (int e = 0; e < 4; ++e) {
            const float xc = fminf(fmaxf(xs[e], -1.0f), 1.0f);
            const float u = fmaf(xc, 6.5f, 6.5f);        // knot units [0,13]
            const float jf = fminf(truncf(u), 12.0f);
            const float tt = u - jf;                     // [0,1]
            const int j = (int)jf;

            const float4 a = lbase[e * 32 + j * PROWS];  // 1x ds_read_b128
            float r = fmaf(a.w, tt, a.z);
            r = fmaf(r, tt, a.y);
            r = fmaf(r, tt, a.x);
            // x==+1 (j=12, tt=1) / x==-1 (j=0, tt=0): zero pads give ~0
            // (<= ~1e-7), matching the reference's empty-indicator edges.
            res[e] = r;
        }
        ov[k].x = res[0]; ov[k].y = res[1]; ov[k].z = res[2]; ov[k].w = res[3];
    }

    // Phase C: issue all 8 NT stores; nothing waits on their retirement.
    #pragma unroll
    for (int k = 0; k < ITERS; ++k) {
        __builtin_nontemporal_store(ov[k], reinterpret_cast<f32x4*>(out) + E4[k]);
    }
}

extern "C" void kernel_launch(void* const* d_in, const int* in_sizes, int n_in,
                              void* d_out, int out_size, void* d_ws, size_t ws_size,
                              hipStream_t stream) {
    const float* x = (const float*)d_in[0];
    const float* coeff = (const float*)d_in[1];
    float* out = (float*)d_out;
    hipLaunchKernelGGL(bspline_act_kernel, dim3(GRID), dim3(THREADS), 0, stream,
                       x, coeff, out);
}